// Round 4
// baseline (538.058 us; speedup 1.0000x reference)
//
#include <hip/hip_runtime.h>
#include <cstddef>

// Shapes
constexpr int H  = 256;
constexpr int Bb = 128;
constexpr int T  = 2048;
constexpr int V  = 32000;
constexpr int SPLITS = 16;          // T-chunks for attention pass
constexpr int TC = T / SPLITS;      // 128 timesteps per block (32 per wave)
constexpr int NPART = SPLITS * 4;   // 64 ctx partials per b
constexpr int NVB = V / 128;        // 250 logits blocks

typedef __attribute__((ext_vector_type(8))) short short8;
typedef __attribute__((ext_vector_type(4))) float f32x4;

// round-to-nearest-even fp32 -> bf16 (inputs finite)
__device__ __forceinline__ unsigned short bf1(float a) {
  unsigned u = __builtin_bit_cast(unsigned, a);
  return (unsigned short)((u + 0x7fffu + ((u >> 16) & 1u)) >> 16);
}
__device__ __forceinline__ unsigned bfpack2(float a, float b) {
  unsigned ua = __builtin_bit_cast(unsigned, a);
  unsigned ub = __builtin_bit_cast(unsigned, b);
  ua = (ua + 0x7fffu + ((ua >> 16) & 1u)) >> 16;
  ub = (ub + 0x7fffu + ((ub >> 16) & 1u)) & 0xffff0000u;
  return ua | ub;
}

// Manual grid barrier (all 250 blocks co-resident: 250 <= 256 CUs, 1 blk/CU
// resource need). Monotonic counter, re-zeroed each call by k_smx_gru.
__device__ __forceinline__ void gsync(int* bar, int target) {
  __syncthreads();
  if (threadIdx.x == 0) {
    __threadfence();
    __hip_atomic_fetch_add(bar, 1, __ATOMIC_RELEASE, __HIP_MEMORY_SCOPE_AGENT);
    while (__hip_atomic_load(bar, __ATOMIC_ACQUIRE, __HIP_MEMORY_SCOPE_AGENT) < target)
      __builtin_amdgcn_s_sleep(8);
  }
  __syncthreads();
}

// ---------------------------------------------------------------------------
// K1: fused scores + unnormalized ctx partials. One pass over enc (256 MB).
// grid (SPLITS, B), block 256 = 4 waves; wave owns 32 consecutive t.
// No barriers / no LDS in the hot loop; 6x shfl_xor butterfly per score.
// ---------------------------------------------------------------------------
__global__ __launch_bounds__(256) void k_attn(
    const float* __restrict__ enc, const float* __restrict__ hidden,
    const float* __restrict__ attn_W, const float* __restrict__ attn_b,
    float* __restrict__ scores, float* __restrict__ ctx_part) {
  const int b = blockIdx.y, chunk = blockIdx.x;
  const int tid = threadIdx.x, lane = tid & 63, wave = tid >> 6;

  const float4 we = *(const float4*)(attn_W + H + lane * 4);
  const float4 wh = *(const float4*)(attn_W + lane * 4);
  const float4 hv = *(const float4*)(hidden + (size_t)b * H + lane * 4);

  float hb = fmaf(wh.x, hv.x, fmaf(wh.y, hv.y, fmaf(wh.z, hv.z, wh.w * hv.w)));
  #pragma unroll
  for (int off = 1; off < 64; off <<= 1) hb += __shfl_xor(hb, off);
  hb += attn_b[0];

  const int t0 = chunk * TC + wave * 32;
  const float* base = enc + (size_t)t0 * (Bb * H) + (size_t)b * H + lane * 4;

  float4 acc = {0.f, 0.f, 0.f, 0.f};
  for (int i = 0; i < 32; i += 4) {
    float4 e0 = *(const float4*)(base + (size_t)(i + 0) * (Bb * H));
    float4 e1 = *(const float4*)(base + (size_t)(i + 1) * (Bb * H));
    float4 e2 = *(const float4*)(base + (size_t)(i + 2) * (Bb * H));
    float4 e3 = *(const float4*)(base + (size_t)(i + 3) * (Bb * H));

    float p0 = fmaf(e0.x, we.x, fmaf(e0.y, we.y, fmaf(e0.z, we.z, e0.w * we.w)));
    float p1 = fmaf(e1.x, we.x, fmaf(e1.y, we.y, fmaf(e1.z, we.z, e1.w * we.w)));
    float p2 = fmaf(e2.x, we.x, fmaf(e2.y, we.y, fmaf(e2.z, we.z, e2.w * we.w)));
    float p3 = fmaf(e3.x, we.x, fmaf(e3.y, we.y, fmaf(e3.z, we.z, e3.w * we.w)));
    #pragma unroll
    for (int off = 1; off < 64; off <<= 1) {
      p0 += __shfl_xor(p0, off);
      p1 += __shfl_xor(p1, off);
      p2 += __shfl_xor(p2, off);
      p3 += __shfl_xor(p3, off);
    }
    float s0 = p0 + hb, s1 = p1 + hb, s2 = p2 + hb, s3 = p3 + hb;
    float w0 = __expf(s0), w1 = __expf(s1), w2 = __expf(s2), w3 = __expf(s3);

    acc.x = fmaf(w0, e0.x, fmaf(w1, e1.x, fmaf(w2, e2.x, fmaf(w3, e3.x, acc.x))));
    acc.y = fmaf(w0, e0.y, fmaf(w1, e1.y, fmaf(w2, e2.y, fmaf(w3, e3.y, acc.y))));
    acc.z = fmaf(w0, e0.z, fmaf(w1, e1.z, fmaf(w2, e2.z, fmaf(w3, e3.z, acc.z))));
    acc.w = fmaf(w0, e0.w, fmaf(w1, e1.w, fmaf(w2, e2.w, fmaf(w3, e3.w, acc.w))));

    if (lane == 0) {
      float4 sv = {s0, s1, s2, s3};
      *(float4*)(scores + (size_t)b * T + t0 + i) = sv;
    }
  }
  float* cp = ctx_part + ((size_t)b * NPART + chunk * 4 + wave) * H + lane * 4;
  *(float4*)cp = acc;
}

// ---------------------------------------------------------------------------
// K2: softmax (exact) -> attn_w; combine ctx partials -> ctx; emb + comb
// linear + ReLU + GRU cell -> h_new (fp32 + bf16). Also zeroes the grid
// barrier for K3. grid B, block 256.
// ---------------------------------------------------------------------------
__global__ __launch_bounds__(256) void k_smx_gru(
    const float* __restrict__ scores, const float* __restrict__ ctx_part,
    const int* __restrict__ tokens, const float* __restrict__ hidden,
    const float* __restrict__ emb_table,
    const float* __restrict__ comb_W, const float* __restrict__ comb_b,
    const float* __restrict__ Wih, const float* __restrict__ Whh,
    const float* __restrict__ bih, const float* __restrict__ bhh,
    float* __restrict__ attn_o, float* __restrict__ ctx_o,
    float* __restrict__ hnew, unsigned short* __restrict__ hnewb,
    int* __restrict__ bar) {
  const int b = blockIdx.x, tid = threadIdx.x;
  const int lane = tid & 63, wave = tid >> 6;
  __shared__ float red[4];
  __shared__ float m_sh, l_sh;
  __shared__ __align__(16) float x2[2 * H];
  __shared__ __align__(16) float hid[H];
  __shared__ __align__(16) float xs[H];

  if (b == 0 && tid == 0) bar[0] = 0;   // re-arm grid barrier (ws poisoned)

  // ---- softmax over T=2048 scores ----
  const float* sb = scores + (size_t)b * T;
  float s[8];
  #pragma unroll
  for (int q = 0; q < 8; q++) s[q] = sb[tid + 256 * q];

  float mx = s[0];
  #pragma unroll
  for (int q = 1; q < 8; q++) mx = fmaxf(mx, s[q]);
  #pragma unroll
  for (int off = 1; off < 64; off <<= 1) mx = fmaxf(mx, __shfl_xor(mx, off));
  if (lane == 0) red[wave] = mx;
  __syncthreads();
  if (tid == 0) m_sh = fmaxf(fmaxf(red[0], red[1]), fmaxf(red[2], red[3]));
  __syncthreads();
  const float m = m_sh;

  float w[8];
  float ps = 0.f;
  #pragma unroll
  for (int q = 0; q < 8; q++) { w[q] = __expf(s[q] - m); ps += w[q]; }
  #pragma unroll
  for (int off = 1; off < 64; off <<= 1) ps += __shfl_xor(ps, off);
  __syncthreads();
  if (lane == 0) red[wave] = ps;
  __syncthreads();
  if (tid == 0) l_sh = red[0] + red[1] + red[2] + red[3];
  __syncthreads();
  const float inv = 1.f / l_sh;

  #pragma unroll
  for (int q = 0; q < 8; q++) attn_o[(size_t)b * T + tid + 256 * q] = w[q] * inv;

  float c = 0.f;
  for (int si = 0; si < NPART; si++)
    c += ctx_part[((size_t)b * NPART + si) * H + tid];
  const float ctxv = c * __expf(-m) * inv;
  ctx_o[(size_t)b * H + tid] = ctxv;

  // ---- comb + GRU ----
  const int tok = tokens[b];
  x2[tid]     = emb_table[(size_t)tok * H + tid];
  x2[H + tid] = ctxv;
  hid[tid]    = hidden[(size_t)b * H + tid];
  __syncthreads();

  {
    const float4* wr = (const float4*)(comb_W + (size_t)tid * (2 * H));
    const float4* xr = (const float4*)x2;
    float a = 0.f;
    #pragma unroll 8
    for (int k = 0; k < (2 * H) / 4; k++) {
      float4 ww = wr[k], x = xr[k];
      a += ww.x * x.x + ww.y * x.y + ww.z * x.z + ww.w * x.w;
    }
    a += comb_b[tid];
    xs[tid] = fmaxf(a, 0.f);
  }
  __syncthreads();

  auto dot256 = [](const float* __restrict__ row, const float* __restrict__ v) -> float {
    const float4* r4 = (const float4*)row;
    const float4* v4 = (const float4*)v;
    float a = 0.f;
    #pragma unroll 8
    for (int k = 0; k < H / 4; k++) {
      float4 ww = r4[k], x = v4[k];
      a += ww.x * x.x + ww.y * x.y + ww.z * x.z + ww.w * x.w;
    }
    return a;
  };

  float gxr = dot256(Wih + (size_t)tid * H,           xs) + bih[tid];
  float gxz = dot256(Wih + (size_t)(tid + H) * H,     xs) + bih[tid + H];
  float gxn = dot256(Wih + (size_t)(tid + 2 * H) * H, xs) + bih[tid + 2 * H];
  float ghr = dot256(Whh + (size_t)tid * H,           hid) + bhh[tid];
  float ghz = dot256(Whh + (size_t)(tid + H) * H,     hid) + bhh[tid + H];
  float ghn = dot256(Whh + (size_t)(tid + 2 * H) * H, hid) + bhh[tid + 2 * H];

  float r = 1.f / (1.f + __expf(-(gxr + ghr)));
  float z = 1.f / (1.f + __expf(-(gxz + ghz)));
  float n = tanhf(gxn + r * ghn);
  float hv = (1.f - z) * n + z * hid[tid];
  hnew[(size_t)b * H + tid] = hv;
  hnewb[(size_t)b * H + tid] = bf1(hv);
}

// ---------------------------------------------------------------------------
// K3 (250 blocks, all co-resident): logits GEMM (bf16 MFMA 16x16x32), acc in
// registers across two manual grid barriers; logp = acc + bias - lse written
// once — raw logits never touch HBM.
// Layouts (m89): A[m=lane&15][k=quad*8+j]; C/D col=lane&15, row=quad*4+reg.
// ---------------------------------------------------------------------------
constexpr int LSTR = 72;   // shorts per LDS row (64 data + 8 pad) = 144 B
__global__ __launch_bounds__(256) void k_logits_fused(
    const unsigned short* __restrict__ hnewb, const float* __restrict__ out_W,
    const float* __restrict__ out_b, float* __restrict__ logp,
    float2* __restrict__ part, float* __restrict__ lse_g,
    int* __restrict__ bar) {
  const int tid = threadIdx.x;
  const int lane = tid & 63, wave = tid >> 6;
  const int blk = blockIdx.x;
  const int v0 = blk * 128;
  const int r16 = lane & 15, quad = lane >> 4;

  __shared__ __align__(16) short lA[128 * LSTR];
  __shared__ __align__(16) short lB[128 * LSTR];
  __shared__ float2 lred[4 * 128];
  __shared__ float lse_s[128];

  f32x4 acc[8][2];
  #pragma unroll
  for (int mt = 0; mt < 8; mt++) {
    acc[mt][0] = (f32x4){0.f, 0.f, 0.f, 0.f};
    acc[mt][1] = (f32x4){0.f, 0.f, 0.f, 0.f};
  }

  for (int k0 = 0; k0 < H; k0 += 64) {
    #pragma unroll
    for (int q = 0; q < 4; q++) {
      int idx = q * 256 + tid;
      int row = idx >> 3, c8 = idx & 7;
      f32x4 v = *(const f32x4*)(hnewb + (size_t)row * H + k0 + c8 * 8);
      *(f32x4*)(&lA[row * LSTR + c8 * 8]) = v;
    }
    #pragma unroll
    for (int q = 0; q < 8; q++) {
      int idx = q * 256 + tid;
      int row = idx >> 4, c4 = idx & 15;
      f32x4 wv = *(const f32x4*)(out_W + (size_t)(v0 + row) * H + k0 + c4 * 4);
      uint2 p;
      p.x = bfpack2(wv.x, wv.y);
      p.y = bfpack2(wv.z, wv.w);
      *(uint2*)(&lB[row * LSTR + c4 * 4]) = p;
    }
    __syncthreads();
    #pragma unroll
    for (int ks = 0; ks < 2; ks++) {
      short8 bf[2];
      #pragma unroll
      for (int nt = 0; nt < 2; nt++) {
        int row = wave * 32 + nt * 16 + r16;
        bf[nt] = *(const short8*)(&lB[row * LSTR + ks * 32 + quad * 8]);
      }
      #pragma unroll
      for (int mt = 0; mt < 8; mt++) {
        short8 af = *(const short8*)(&lA[(mt * 16 + r16) * LSTR + ks * 32 + quad * 8]);
        acc[mt][0] = __builtin_amdgcn_mfma_f32_16x16x32_bf16(af, bf[0], acc[mt][0], 0, 0, 0);
        acc[mt][1] = __builtin_amdgcn_mfma_f32_16x16x32_bf16(af, bf[1], acc[mt][1], 0, 0, 0);
      }
    }
    __syncthreads();
  }

  const float bias0 = out_b[v0 + wave * 32 + r16];
  const float bias1 = out_b[v0 + wave * 32 + 16 + r16];

  // phase 1: per-block per-row online (m,l) over this block's 32 cols/wave
  #pragma unroll
  for (int mt = 0; mt < 8; mt++) {
    float pm[4], pl[4];
    #pragma unroll
    for (int r = 0; r < 4; r++) {
      float x0 = acc[mt][0][r] + bias0;
      float x1 = acc[mt][1][r] + bias1;
      float mm = fmaxf(x0, x1);
      pm[r] = mm;
      pl[r] = __expf(x0 - mm) + __expf(x1 - mm);
    }
    #pragma unroll
    for (int off = 1; off < 16; off <<= 1) {
      #pragma unroll
      for (int r = 0; r < 4; r++) {
        float mo = __shfl_xor(pm[r], off), lo = __shfl_xor(pl[r], off);
        float nm = fmaxf(pm[r], mo);
        pl[r] = pl[r] * __expf(pm[r] - nm) + lo * __expf(mo - nm);
        pm[r] = nm;
      }
    }
    if (r16 == 0) {
      #pragma unroll
      for (int r = 0; r < 4; r++)
        lred[wave * 128 + mt * 16 + quad * 4 + r] = make_float2(pm[r], pl[r]);
    }
  }
  __syncthreads();
  if (tid < 128) {
    float2 p = lred[tid];
    #pragma unroll
    for (int w2 = 1; w2 < 4; w2++) {
      float2 q = lred[w2 * 128 + tid];
      float nm = fmaxf(p.x, q.x);
      p.y = p.y * __expf(p.x - nm) + q.y * __expf(q.x - nm);
      p.x = nm;
    }
    part[(size_t)tid * NVB + blk] = p;
  }

  gsync(bar, NVB);

  // phase 2: blocks < 128 reduce NVB partials for row b=blk -> lse_g[b]
  if (blk < 128) {
    float pm = -1e30f, pl = 0.f;
    if (tid < NVB) {
      float2 p = part[(size_t)blk * NVB + tid];
      pm = p.x; pl = p.y;
    }
    #pragma unroll
    for (int off = 1; off < 64; off <<= 1) {
      float mo = __shfl_xor(pm, off), lo = __shfl_xor(pl, off);
      float nm = fmaxf(pm, mo);
      pl = pl * __expf(pm - nm) + lo * __expf(mo - nm);
      pm = nm;
    }
    if (lane == 0) lred[wave] = make_float2(pm, pl);
    __syncthreads();
    if (tid == 0) {
      float2 p = lred[0];
      #pragma unroll
      for (int w2 = 1; w2 < 4; w2++) {
        float2 q = lred[w2];
        float nm = fmaxf(p.x, q.x);
        p.y = p.y * __expf(p.x - nm) + q.y * __expf(q.x - nm);
        p.x = nm;
      }
      lse_g[blk] = p.x + logf(p.y);
    }
  }

  gsync(bar, 2 * NVB);

  // phase 3: write logp = acc + bias - lse
  if (tid < 128) lse_s[tid] = lse_g[tid];
  __syncthreads();
  #pragma unroll
  for (int nt = 0; nt < 2; nt++) {
    int col = v0 + wave * 32 + nt * 16 + r16;
    float bias = nt ? bias1 : bias0;
    #pragma unroll
    for (int mt = 0; mt < 8; mt++) {
      int brow = mt * 16 + quad * 4;
      #pragma unroll
      for (int r = 0; r < 4; r++)
        logp[(size_t)(brow + r) * V + col] = acc[mt][nt][r] + bias - lse_s[brow + r];
    }
  }
}

// ---------------------------------------------------------------------------
extern "C" void kernel_launch(void* const* d_in, const int* in_sizes, int n_in,
                              void* d_out, int out_size, void* d_ws, size_t ws_size,
                              hipStream_t stream) {
  const int*   tokens = (const int*)d_in[0];
  const float* hidden = (const float*)d_in[1];
  const float* enc    = (const float*)d_in[2];
  const float* emb    = (const float*)d_in[3];
  const float* attn_W = (const float*)d_in[4];
  const float* attn_b = (const float*)d_in[5];
  const float* comb_W = (const float*)d_in[6];
  const float* comb_b = (const float*)d_in[7];
  const float* Wih    = (const float*)d_in[8];
  const float* Whh    = (const float*)d_in[9];
  const float* bih    = (const float*)d_in[10];
  const float* bhh    = (const float*)d_in[11];
  const float* out_W  = (const float*)d_in[12];
  const float* out_b  = (const float*)d_in[13];

  float* out    = (float*)d_out;
  float* logp   = out;                                   // (1,B,V)
  float* hnew   = out + (size_t)Bb * V;                  // (1,B,H)
  float* attn_o = hnew + (size_t)Bb * H;                 // (B,T,1)
  float* ctx_o  = attn_o + (size_t)Bb * T;               // (1,B,H)

  float* ws       = (float*)d_ws;
  float* scores   = ws;                                           // B*T
  float* ctx_part = ws + (size_t)Bb * T;                          // B*NPART*H
  float2* part    = (float2*)(ctx_part + (size_t)Bb * NPART * H); // 128*NVB
  float* lse_g    = (float*)(part + (size_t)Bb * NVB);            // 128
  unsigned short* hnewb = (unsigned short*)(lse_g + Bb);          // B*H bf16
  int* bar        = (int*)(hnewb + (size_t)Bb * H);               // 1 int

  k_attn<<<dim3(SPLITS, Bb), 256, 0, stream>>>(enc, hidden, attn_W, attn_b, scores, ctx_part);
  k_smx_gru<<<dim3(Bb), 256, 0, stream>>>(scores, ctx_part, tokens, hidden, emb,
                                          comb_W, comb_b, Wih, Whh, bih, bhh,
                                          attn_o, ctx_o, hnew, hnewb, bar);
  k_logits_fused<<<dim3(NVB), 256, 0, stream>>>(hnewb, out_W, out_b, logp,
                                                part, lse_g, bar);
}